// Round 1
// baseline (1013.052 us; speedup 1.0000x reference)
//
#include <hip/hip_runtime.h>

// VQ-VAE quantize: input (16,64,64,64) f32, embeddings (64,2048) f32.
// Outputs concat in d_out: quantize_st[4194304], loss[1], embed_ind[65536] (as float).
//
// Correctness-critical: argmin must match numpy fp32 semantics.
//   dist = fl( fl(sx - 2*dot) + se ),  dot = sequential-k FMA (BLAS order),
//   sx = numpy pairwise (8 accumulators + tree), se = sequential axis-0 sum,
//   argmin = first index of minimum (strict <, ascending j).

#define HW     4096      // 64*64
#define CHW    262144    // 64*4096
#define NE     2048
#define OUT_Q  4194304   // NPIX*DIM
#define WS_ET  0         // ET[j][k]: 2048*64 floats
#define WS_SE  131072    // se[j]: 2048 floats
#define WS_ACC 133120    // loss accumulator: 1 float

__global__ __launch_bounds__(256) void vq_prep(const float* __restrict__ emb,
                                               float* __restrict__ ws) {
  int bid = blockIdx.x;
  if (bid < 512) {
    // transpose: ET[j*64+k] = emb[k*2048+j]; t = k*2048+j (coalesced read)
    int t = bid * 256 + threadIdx.x;
    int k = t >> 11;
    int j = t & 2047;
    ws[WS_ET + j * 64 + k] = emb[t];
  } else {
    // se[j] = sum_k fl(e_kj^2), sequential over k (numpy axis-0 reduce order)
    int j = (bid - 512) * 256 + threadIdx.x;
    float s = 0.0f;
    for (int k = 0; k < 64; ++k) {
      float e = emb[k * NE + j];
      s = __fadd_rn(s, __fmul_rn(e, e));
    }
    ws[WS_SE + j] = s;
    if (j == 0) ws[WS_ACC] = 0.0f;
  }
}

__global__ __launch_bounds__(512, 4) void vq_main(const float* __restrict__ inp,
                                                  const float* __restrict__ emb,
                                                  const float* __restrict__ ws,
                                                  float* __restrict__ out,
                                                  float* __restrict__ loss_acc) {
  __shared__ float rv[8][64];
  __shared__ int   ri[8][64];
  __shared__ float ls[512];

  const int tid  = threadIdx.x;
  const int lane = tid & 63;
  const int wv   = tid >> 6;            // wave id = code-range split 0..7
  const int n    = blockIdx.x * 64 + lane;   // pixel id in (B,H,W) flat order
  const int b    = n >> 12;
  const int rem  = n & 4095;            // h*64+w
  const float* xp = inp + (size_t)b * CHW + rem;

  // x[c] in registers, statically indexed only
  float x[64];
#pragma unroll
  for (int c = 0; c < 64; ++c) x[c] = xp[c * HW];

  // sx: numpy pairwise sum of squares (8 accumulators over 8 chunks, then tree)
  float r[8];
#pragma unroll
  for (int i = 0; i < 8; ++i) r[i] = __fmul_rn(x[i], x[i]);
#pragma unroll
  for (int blk = 1; blk < 8; ++blk) {
#pragma unroll
    for (int i = 0; i < 8; ++i)
      r[i] = __fadd_rn(r[i], __fmul_rn(x[blk * 8 + i], x[blk * 8 + i]));
  }
  const float sx =
      __fadd_rn(__fadd_rn(__fadd_rn(r[0], r[1]), __fadd_rn(r[2], r[3])),
                __fadd_rn(__fadd_rn(r[4], r[5]), __fadd_rn(r[6], r[7])));

  const float* ET = ws + WS_ET;   // ET[j][k], row = 256B contiguous (uniform loads)
  const float* se = ws + WS_SE;

  float best = 3.402823466e38f;
  int   bi   = 0;
  const int j0 = wv * 256;        // this wave's ascending code range
#pragma unroll 2
  for (int j = j0; j < j0 + 256; ++j) {
    const float4* ej = reinterpret_cast<const float4*>(ET + j * 64);
    float dot = 0.0f;
#pragma unroll
    for (int kk = 0; kk < 16; ++kk) {
      float4 e4 = ej[kk];         // wave-uniform address -> s_load, SGPR operand
      dot = __fmaf_rn(x[4 * kk + 0], e4.x, dot);
      dot = __fmaf_rn(x[4 * kk + 1], e4.y, dot);
      dot = __fmaf_rn(x[4 * kk + 2], e4.z, dot);
      dot = __fmaf_rn(x[4 * kk + 3], e4.w, dot);
    }
    float dist = __fadd_rn(__fsub_rn(sx, __fmul_rn(2.0f, dot)), se[j]);
    if (dist < best) { best = dist; bi = j; }   // strict <: first index wins ties
  }

  rv[wv][lane] = best;
  ri[wv][lane] = bi;
  __syncthreads();

  // merge across the 8 waves (ranges ascending in j -> strict < keeps lowest j)
  float bv  = rv[0][lane];
  int   bix = ri[0][lane];
#pragma unroll
  for (int s = 1; s < 8; ++s) {
    float v = rv[s][lane];
    if (v < bv) { bv = v; bix = ri[s][lane]; }
  }

  // epilogue: pixel = lane, channels [wv*8, wv*8+8)
  float lsum = 0.0f;
#pragma unroll
  for (int i = 0; i < 8; ++i) {
    int c = wv * 8 + i;
    float xv = xp[c * HW];                 // re-read (L1 hot) to avoid dyn-indexed regs
    float q  = emb[c * NE + bix];          // gather code value
    float d  = __fsub_rn(q, xv);
    out[(size_t)b * CHW + c * HW + rem] = __fadd_rn(xv, d);  // x + (q - x)
    lsum = __fadd_rn(lsum, __fmul_rn(d, d));
  }
  if (wv == 0) out[OUT_Q + 1 + n] = (float)bix;

  // block-reduce loss partials, one atomic per block
  ls[tid] = lsum;
  __syncthreads();
#pragma unroll
  for (int off = 256; off > 0; off >>= 1) {
    if (tid < off) ls[tid] = __fadd_rn(ls[tid], ls[tid + off]);
    __syncthreads();
  }
  if (tid == 0) atomicAdd(loss_acc, ls[0]);
}

__global__ void vq_final(const float* __restrict__ ws, float* __restrict__ out) {
  float m = ws[WS_ACC] / 4194304.0f;       // exact pow2 divide
  out[OUT_Q] = __fadd_rn(m, __fmul_rn(0.25f, m));   // mean + 0.25*mean
}

extern "C" void kernel_launch(void* const* d_in, const int* in_sizes, int n_in,
                              void* d_out, int out_size, void* d_ws, size_t ws_size,
                              hipStream_t stream) {
  const float* inp = (const float*)d_in[0];
  const float* emb = (const float*)d_in[1];
  float* out = (float*)d_out;
  float* ws  = (float*)d_ws;

  vq_prep<<<520, 256, 0, stream>>>(emb, ws);
  vq_main<<<1024, 512, 0, stream>>>(inp, emb, ws, out, ws + WS_ACC);
  vq_final<<<1, 1, 0, stream>>>(ws, out);
}